// Round 1
// baseline (6487.890 us; speedup 1.0000x reference)
//
#include <hip/hip_runtime.h>
#include <hip/hip_fp16.h>

typedef unsigned short u16;
typedef unsigned int u32;
typedef __attribute__((ext_vector_type(8))) short short8;   // 8 x bf16 (4 VGPRs)
typedef __attribute__((ext_vector_type(4))) float f32x4;

#define EMBED 768
#define HH 128
#define WW 128
#define WF 65            // 128/2 + 1
#define NPOS (HH*WF)     // 8320 spectral positions
#define NPIX (HH*WW)     // 16384 pixels
#define LATENT 3072
#define TWO_PI_OVER_128 0.049087385212340517f

__device__ __forceinline__ u16 f2b(float x) {
    u32 u = __float_as_uint(x);
    u32 r = u + 0x7FFFu + ((u >> 16) & 1u);   // RNE
    return (u16)(r >> 16);
}
__device__ __forceinline__ float b2f(u16 v) {
    return __uint_as_float(((u32)v) << 16);
}

// ---------------------------------------------------------------------------
// LayerNorm over C=768. One 256-thread block per row; writes f32 and/or bf16.
// ---------------------------------------------------------------------------
__global__ __launch_bounds__(256)
void layernorm_k(const float* __restrict__ x, const float* __restrict__ w,
                 const float* __restrict__ bb, float* __restrict__ of,
                 u16* __restrict__ ob)
{
    int row = blockIdx.x;
    int t = threadIdx.x;
    const float* xr = x + (size_t)row * EMBED;
    float v0 = xr[t], v1 = xr[t + 256], v2 = xr[t + 512];
    float s = v0 + v1 + v2;
    float sq = v0 * v0 + v1 * v1 + v2 * v2;
    for (int off = 32; off > 0; off >>= 1) {
        s  += __shfl_xor(s, off, 64);
        sq += __shfl_xor(sq, off, 64);
    }
    __shared__ float rs[4], rq[4];
    int lane = t & 63, wv = t >> 6;
    if (lane == 0) { rs[wv] = s; rq[wv] = sq; }
    __syncthreads();
    s  = rs[0] + rs[1] + rs[2] + rs[3];
    sq = rq[0] + rq[1] + rq[2] + rq[3];
    float mean = s * (1.f / 768.f);
    float var  = sq * (1.f / 768.f) - mean * mean;
    float rstd = rsqrtf(var + 1e-5f);
    #pragma unroll
    for (int e = 0; e < 3; ++e) {
        int c = t + e * 256;
        float v = (e == 0 ? v0 : (e == 1 ? v1 : v2));
        float o = (v - mean) * rstd * w[c] + bb[c];
        size_t g = (size_t)row * EMBED + c;
        if (of) of[g] = o;
        if (ob) ob[g] = f2b(o);
    }
}

// ---------------------------------------------------------------------------
// Forward rfft along W: per (h, ctile64), T[h,k,c] = sum_w x[h,w,c] e^{-2pi i k w/128}
// ---------------------------------------------------------------------------
__global__ __launch_bounds__(256)
void rfft_w(const float* __restrict__ X, float* __restrict__ Tr, float* __restrict__ Ti)
{
    int h = blockIdx.x;
    int c0 = blockIdx.y << 6;
    __shared__ float xs[128 * 64];
    __shared__ float cs[128], sn[128];
    int t = threadIdx.x;
    for (int idx = t; idx < 8192; idx += 256)
        xs[idx] = X[((size_t)(h * WW + (idx >> 6))) * EMBED + c0 + (idx & 63)];
    if (t < 128) { float a = TWO_PI_OVER_128 * t; float ss, cc; sincosf(a, &ss, &cc); cs[t] = cc; sn[t] = ss; }
    __syncthreads();
    int c = t & 63, k0 = t >> 6;
    for (int k = k0; k < WF; k += 4) {
        float ar = 0.f, ai = 0.f;
        int j = 0;
        for (int w = 0; w < 128; ++w) {
            float v = xs[(w << 6) | c];
            ar += v * cs[j];
            ai -= v * sn[j];
            j = (j + k) & 127;
        }
        size_t g = ((size_t)(h * WF + k)) * EMBED + c0 + c;
        Tr[g] = ar; Ti[g] = ai;
    }
}

// ---------------------------------------------------------------------------
// Forward complex fft along H with 1/128 ortho scale.
// mode 0: f32 out at [(u*65+k)*768+c]. mode 1: bf16 packed [re rows | im rows].
// ---------------------------------------------------------------------------
__global__ __launch_bounds__(256)
void fft_h_fwd(const float* __restrict__ Tr, const float* __restrict__ Ti,
               float* __restrict__ Xr, float* __restrict__ Xi,
               u16* __restrict__ Mri, int mode)
{
    int k = blockIdx.x;
    int c0 = blockIdx.y << 5;
    __shared__ float sr[128 * 32], si[128 * 32];
    __shared__ float cs[128], sn[128];
    int t = threadIdx.x;
    for (int idx = t; idx < 4096; idx += 256) {
        int h = idx >> 5, c = idx & 31;
        size_t g = ((size_t)(h * WF + k)) * EMBED + c0 + c;
        sr[idx] = Tr[g]; si[idx] = Ti[g];
    }
    if (t < 128) { float a = TWO_PI_OVER_128 * t; float ss, cc; sincosf(a, &ss, &cc); cs[t] = cc; sn[t] = ss; }
    __syncthreads();
    int c = t & 31, u0 = t >> 5;
    for (int u = u0; u < 128; u += 8) {
        float ar = 0.f, ai = 0.f;
        int j = 0;
        for (int h = 0; h < 128; ++h) {
            float tr = sr[(h << 5) + c], ti = si[(h << 5) + c];
            float wc = cs[j], ws = sn[j];
            ar += tr * wc + ti * ws;     // (tr+i ti)(cos - i sin)
            ai += ti * wc - tr * ws;
            j = (j + u) & 127;
        }
        ar *= (1.f / 128.f); ai *= (1.f / 128.f);
        size_t p = (size_t)(u * WF + k);
        if (mode == 0) {
            Xr[p * EMBED + c0 + c] = ar;
            Xi[p * EMBED + c0 + c] = ai;
        } else {
            Mri[p * EMBED + c0 + c] = f2b(ar);
            Mri[(p + NPOS) * EMBED + c0 + c] = f2b(ai);
        }
    }
}

// ---------------------------------------------------------------------------
// Inverse complex fft along H (e^{+i}, no scale). In: [(u*65+k)*768+c]. Out: [(h*65+k)*768+c].
// ---------------------------------------------------------------------------
__global__ __launch_bounds__(256)
void ifft_h(const float* __restrict__ Qr, const float* __restrict__ Qi,
            float* __restrict__ Sr, float* __restrict__ Si)
{
    int k = blockIdx.x;
    int c0 = blockIdx.y << 5;
    __shared__ float sr[128 * 32], si[128 * 32];
    __shared__ float cs[128], sn[128];
    int t = threadIdx.x;
    for (int idx = t; idx < 4096; idx += 256) {
        int u = idx >> 5, c = idx & 31;
        size_t g = ((size_t)(u * WF + k)) * EMBED + c0 + c;
        sr[idx] = Qr[g]; si[idx] = Qi[g];
    }
    if (t < 128) { float a = TWO_PI_OVER_128 * t; float ss, cc; sincosf(a, &ss, &cc); cs[t] = cc; sn[t] = ss; }
    __syncthreads();
    int c = t & 31, h0 = t >> 5;
    for (int h = h0; h < 128; h += 8) {
        float ar = 0.f, ai = 0.f;
        int j = 0;
        for (int u = 0; u < 128; ++u) {
            float tr = sr[(u << 5) + c], ti = si[(u << 5) + c];
            float wc = cs[j], ws = sn[j];
            ar += tr * wc - ti * ws;     // (tr+i ti)(cos + i sin)
            ai += ti * wc + tr * ws;
            j = (j + h) & 127;
        }
        size_t g = ((size_t)(h * WF + k)) * EMBED + c0 + c;
        Sr[g] = ar; Si[g] = ai;
    }
}

// ---------------------------------------------------------------------------
// Inverse rfft along W (hermitian recombine, 1/128 scale) + bias(hln) + residual(x).
// Imag parts of k=0 and k=64 dropped (numpy c2r semantics).
// ---------------------------------------------------------------------------
__global__ __launch_bounds__(256)
void irfft_w_add(const float* __restrict__ Sr, const float* __restrict__ Si,
                 const float* __restrict__ hln, const float* __restrict__ xin,
                 float* __restrict__ Y)
{
    int h = blockIdx.x;
    int c0 = blockIdx.y << 6;
    __shared__ float sr[WF * 64], si[WF * 64];
    __shared__ float cs[128], sn[128];
    int t = threadIdx.x;
    for (int idx = t; idx < WF * 64; idx += 256) {
        int k = idx >> 6, c = idx & 63;
        size_t g = ((size_t)(h * WF + k)) * EMBED + c0 + c;
        sr[idx] = Sr[g]; si[idx] = Si[g];
    }
    if (t < 128) { float a = TWO_PI_OVER_128 * t; float ss, cc; sincosf(a, &ss, &cc); cs[t] = cc; sn[t] = ss; }
    __syncthreads();
    int c = t & 63, w0 = t >> 6;
    for (int w = w0; w < 128; w += 4) {
        float acc = sr[c] + ((w & 1) ? -sr[(64 << 6) + c] : sr[(64 << 6) + c]);
        int j = 0;
        for (int k = 1; k < 64; ++k) {
            j = (j + w) & 127;
            acc += 2.f * (sr[(k << 6) + c] * cs[j] - si[(k << 6) + c] * sn[j]);
        }
        acc *= (1.f / 128.f);
        size_t g = ((size_t)(h * WW + w)) * EMBED + c0 + c;
        Y[g] = acc + hln[g] + xin[g];
    }
}

// ---------------------------------------------------------------------------
// Block-diagonal complex matmul (8 blocks of 96x96) with fused epilogue.
// SHRINK=0: +b, complex-modulate with SS (sc=1+s), relu.  SHRINK=1: +b, softshrink.
// ---------------------------------------------------------------------------
template<int SHRINK>
__global__ __launch_bounds__(192)
void blockmm_k(const float* __restrict__ Ir, const float* __restrict__ Ii,
               const float* __restrict__ wmat, const float* __restrict__ bvec,
               const float* __restrict__ SS, float* __restrict__ Or, float* __restrict__ Oi)
{
    int b = blockIdx.y;
    int p0 = blockIdx.x << 4;
    __shared__ __half2 wri[96 * 96];                 // (wr, wi) packed fp16
    __shared__ float xr_s[16 * 96], xi_s[16 * 96];
    int t = threadIdx.x;
    for (int idx = t; idx < 96 * 96; idx += 192) {
        int i = idx / 96, o = idx - i * 96;
        float wr = wmat[((size_t)(b) * 96 + i) * 96 + o];        // w[0][b][i][o]
        float wi = wmat[((size_t)(8 + b) * 96 + i) * 96 + o];    // w[1][b][i][o]
        wri[idx] = __floats2half2_rn(wr, wi);
    }
    for (int idx = t; idx < 16 * 96; idx += 192) {
        int pp = idx / 96, cc = idx - pp * 96;
        size_t g = (size_t)(p0 + pp) * EMBED + b * 96 + cc;
        xr_s[idx] = Ir[g]; xi_s[idx] = Ii[g];
    }
    __syncthreads();
    int o = t % 96, pr = t / 96;
    float br = bvec[b * 96 + o], bi = bvec[(8 + b) * 96 + o];
    for (int pp = pr; pp < 16; pp += 2) {
        float ar = br, ai = bi;
        const float* xrp = &xr_s[pp * 96];
        const float* xip = &xi_s[pp * 96];
        for (int i = 0; i < 96; ++i) {
            float2 wv = __half22float2(wri[i * 96 + o]);
            float xr = xrp[i], xi = xip[i];
            ar += xr * wv.x - xi * wv.y;
            ai += xi * wv.x + xr * wv.y;
        }
        int p = p0 + pp;
        int cg = b * 96 + o;
        size_t og = (size_t)p * EMBED + cg;
        if (SHRINK == 0) {
            float scr = 1.f + SS[(size_t)p * 1536 + cg];
            float shr = SS[(size_t)p * 1536 + 768 + cg];
            float sci = 1.f + SS[((size_t)(NPOS + p)) * 1536 + cg];
            float shi = SS[((size_t)(NPOS + p)) * 1536 + 768 + cg];
            float nr = ar * scr - ai * sci + shr;
            float ni = ai * scr + ar * sci + shi;
            Or[og] = fmaxf(nr, 0.f);
            Oi[og] = fmaxf(ni, 0.f);
        } else {
            float r  = (ar > 0.01f) ? ar - 0.01f : ((ar < -0.01f) ? ar + 0.01f : 0.f);
            float im = (ai > 0.01f) ? ai - 0.01f : ((ai < -0.01f) ? ai + 0.01f : 0.f);
            Or[og] = r; Oi[og] = im;
        }
    }
}

// ---------------------------------------------------------------------------
// f32 -> bf16 conversion (4 elems/thread)
// ---------------------------------------------------------------------------
__global__ __launch_bounds__(256)
void f32_to_bf16_k(const float* __restrict__ in, u16* __restrict__ out, int n4)
{
    int i = blockIdx.x * 256 + threadIdx.x;
    if (i < n4) {
        float4 v = ((const float4*)in)[i];
        ushort4 o;
        o.x = f2b(v.x); o.y = f2b(v.y); o.z = f2b(v.z); o.w = f2b(v.w);
        ((ushort4*)out)[i] = o;
    }
}

// ---------------------------------------------------------------------------
// bf16 MFMA GEMM: C[M,N] = A[M,K] * B[N,K]^T, fp32 accumulate.
// 128x128 tile, BK=64, 256 threads (2x2 waves of 64x64), 16x16x32 MFMA.
// EPI 0: bias+relu -> bf16.   EPI 1: bias+relu -> f32.
// EPI 2: bias, *(1+ss[n]) + ss[n+3072], exact gelu -> bf16 (aux = bf16 SS2 rows, ld 6144).
// EPI 3: bias + aux_f32[m*N+n] -> f32.
// ---------------------------------------------------------------------------
#define BM 128
#define BN 128
#define BK 64
#define LDK 72   // +8 pad: row stride 144 B -> benign 2-way LDS aliasing

template<int EPI>
__global__ __launch_bounds__(256, 2)
void gemm_bt(const u16* __restrict__ A, const u16* __restrict__ B,
             const float* __restrict__ bias, const void* __restrict__ aux,
             void* __restrict__ out, int M, int N, int K)
{
    __shared__ __align__(16) u16 As[BM * LDK];
    __shared__ __align__(16) u16 Bs[BN * LDK];
    int t = threadIdx.x;
    int bn0 = blockIdx.x * BN;
    int bm0 = blockIdx.y * BM;
    int lane = t & 63, wv = t >> 6;
    int wm = (wv & 1) << 6, wn = (wv >> 1) << 6;
    int lr = lane & 15, quad = lane >> 4;

    f32x4 acc[4][4];
    f32x4 zero = {0.f, 0.f, 0.f, 0.f};
    #pragma unroll
    for (int i = 0; i < 4; ++i)
        #pragma unroll
        for (int j = 0; j < 4; ++j) acc[i][j] = zero;

    for (int kt = 0; kt < K; kt += BK) {
        #pragma unroll
        for (int i = 0; i < 4; ++i) {
            int chunk = t + (i << 8);            // 0..1023
            int row = chunk >> 3;
            int kc  = (chunk & 7) << 3;
            *(uint4*)&As[row * LDK + kc] = *(const uint4*)(A + (size_t)(bm0 + row) * K + kt + kc);
            *(uint4*)&Bs[row * LDK + kc] = *(const uint4*)(B + (size_t)(bn0 + row) * K + kt + kc);
        }
        __syncthreads();
        #pragma unroll
        for (int kk = 0; kk < BK; kk += 32) {
            short8 af[4], bf[4];
            #pragma unroll
            for (int i = 0; i < 4; ++i)
                af[i] = *(const short8*)&As[(wm + (i << 4) + lr) * LDK + kk + (quad << 3)];
            #pragma unroll
            for (int j = 0; j < 4; ++j)
                bf[j] = *(const short8*)&Bs[(wn + (j << 4) + lr) * LDK + kk + (quad << 3)];
            #pragma unroll
            for (int i = 0; i < 4; ++i)
                #pragma unroll
                for (int j = 0; j < 4; ++j)
                    acc[i][j] = __builtin_amdgcn_mfma_f32_16x16x32_bf16(af[i], bf[j], acc[i][j], 0, 0, 0);
        }
        __syncthreads();
    }

    // epilogue: D elem (m = quad*4 + r, n = lr) within each 16x16 tile
    #pragma unroll
    for (int j = 0; j < 4; ++j) {
        int gn = bn0 + wn + (j << 4) + lr;
        float bv = bias[gn];
        #pragma unroll
        for (int i = 0; i < 4; ++i) {
            int rm = bm0 + wm + (i << 4) + (quad << 2);
            #pragma unroll
            for (int r = 0; r < 4; ++r) {
                int gm = rm + r;
                float v = acc[i][j][r] + bv;
                size_t oidx = (size_t)gm * N + gn;
                if (EPI == 0) {
                    ((u16*)out)[oidx] = f2b(fmaxf(v, 0.f));
                } else if (EPI == 1) {
                    ((float*)out)[oidx] = fmaxf(v, 0.f);
                } else if (EPI == 2) {
                    const u16* ss = (const u16*)aux;
                    size_t si = (size_t)gm * (2 * LATENT) + gn;
                    float sc = 1.f + b2f(ss[si]);
                    float sh = b2f(ss[si + LATENT]);
                    v = v * sc + sh;
                    v = 0.5f * v * (1.f + erff(v * 0.70710678118f));
                    ((u16*)out)[oidx] = f2b(v);
                } else {
                    const float* y = (const float*)aux;
                    ((float*)out)[oidx] = v + y[oidx];
                }
            }
        }
    }
}

// ---------------------------------------------------------------------------
extern "C" void kernel_launch(void* const* d_in, const int* in_sizes, int n_in,
                              void* d_out, int out_size, void* d_ws, size_t ws_size,
                              hipStream_t stream)
{
    if (n_in < 22 || out_size != NPIX * EMBED) return;

    const float* x    = (const float*)d_in[0];
    const float* mod  = (const float*)d_in[1];
    const float* n1w  = (const float*)d_in[2];
    const float* n1b  = (const float*)d_in[3];
    const float* n2w  = (const float*)d_in[4];
    const float* n2b  = (const float*)d_in[5];
    const float* w1   = (const float*)d_in[6];
    const float* b1   = (const float*)d_in[7];
    const float* w2   = (const float*)d_in[8];
    const float* b2   = (const float*)d_in[9];
    const float* fC1w = (const float*)d_in[10];  // filter c1 (3072,768)
    const float* fC1b = (const float*)d_in[11];
    const float* fC2w = (const float*)d_in[12];  // filter c2 (1536,3072)
    const float* fC2b = (const float*)d_in[13];
    const float* fc1w = (const float*)d_in[14];  // mlp fc1 (3072,768)
    const float* fc1b = (const float*)d_in[15];
    const float* fc2w = (const float*)d_in[16];  // mlp fc2 (768,3072)
    const float* fc2b = (const float*)d_in[17];
    const float* mC1w = (const float*)d_in[18];  // mod cnn c1 (12288,768)
    const float* mC1b = (const float*)d_in[19];
    const float* mC2w = (const float*)d_in[20];  // mod cnn c2 (6144,12288)
    const float* mC2b = (const float*)d_in[21];

    char* ws = (char*)d_ws;
    size_t off = 0;
    auto alloc = [&](size_t bytes) { size_t o = off; off += (bytes + 255) & ~(size_t)255; return o; };

    const size_t F32_PIX = (size_t)NPIX * EMBED * 4;   // 50331648
    const size_t F32_POS = (size_t)NPOS * EMBED * 4;   // 25559040

    float* hln = (float*)(ws + alloc(F32_PIX));
    float* Y   = (float*)(ws + alloc(F32_PIX));
    float* Tr  = (float*)(ws + alloc(F32_POS));        // Tx / Tmod / P_re
    float* Ti  = (float*)(ws + alloc(F32_POS));        // Tx / Tmod / P_im
    float* Xr  = (float*)(ws + alloc(F32_POS));        // X_re / S_re
    float* Xi  = (float*)(ws + alloc(F32_POS));        // X_im / S_im
    u16*   Mri = (u16*)(ws + alloc((size_t)2 * NPOS * EMBED * 2));   // mod spectrum bf16 [re|im]; later h2n
    u16*   modb = (u16*)(ws + alloc((size_t)NPIX * EMBED * 2));
    char*  R1  = ws + alloc((size_t)16640 * 3072 * 2); // H1 / Hm chunk / Hf chunk
    char*  R2  = ws + alloc((size_t)16640 * 1536 * 4); // SS / Qr,Qi / SS2 chunk

    u16* wFc1 = (u16*)(ws + alloc((size_t)3072 * 768 * 2));
    u16* wFc2 = (u16*)(ws + alloc((size_t)1536 * 3072 * 2));
    u16* wfc1 = (u16*)(ws + alloc((size_t)3072 * 768 * 2));
    u16* wfc2 = (u16*)(ws + alloc((size_t)768 * 3072 * 2));
    u16* wMc1 = (u16*)(ws + alloc((size_t)12288 * 768 * 2));
    u16* wMc2 = (u16*)(ws + alloc((size_t)6144 * 12288 * 2));

    if (off > ws_size) return;   // workspace too small: bail (visible as zero output)

    u16*   H1   = (u16*)R1;
    u16*   Hm   = (u16*)R1;
    u16*   Hf   = (u16*)R1;
    float* SS   = (float*)R2;
    float* Qr   = (float*)R2;
    float* Qi   = (float*)(R2 + F32_POS);
    u16*   SS2c = (u16*)R2;
    float* Sr   = Xr;
    float* Si   = Xi;
    float* Pr   = Tr;
    float* Pi   = Ti;
    u16*   h2n  = Mri;

    auto conv = [&](const float* src, u16* dst, size_t n) {
        int n4 = (int)(n >> 2);
        f32_to_bf16_k<<<dim3((n4 + 255) / 256), dim3(256), 0, stream>>>(src, dst, n4);
    };

    // ---- filter branch ----
    layernorm_k<<<dim3(NPIX), dim3(256), 0, stream>>>(x, n1w, n1b, hln, nullptr);
    rfft_w<<<dim3(HH, EMBED / 64), dim3(256), 0, stream>>>(hln, Tr, Ti);
    fft_h_fwd<<<dim3(WF, EMBED / 32), dim3(256), 0, stream>>>(Tr, Ti, Xr, Xi, nullptr, 0);
    rfft_w<<<dim3(HH, EMBED / 64), dim3(256), 0, stream>>>(mod, Tr, Ti);
    fft_h_fwd<<<dim3(WF, EMBED / 32), dim3(256), 0, stream>>>(Tr, Ti, nullptr, nullptr, Mri, 1);

    conv(fC1w, wFc1, (size_t)3072 * 768);
    conv(fC2w, wFc2, (size_t)1536 * 3072);

    // filter cnn: (2*8320 x 768) -> relu -> (x 3072) -> relu -> (x 1536)
    gemm_bt<0><<<dim3(3072 / BN, 16640 / BM), dim3(256), 0, stream>>>(
        Mri, wFc1, fC1b, nullptr, H1, 16640, 3072, 768);
    gemm_bt<1><<<dim3(1536 / BN, 16640 / BM), dim3(256), 0, stream>>>(
        H1, wFc2, fC2b, nullptr, SS, 16640, 1536, 3072);

    // block-diagonal complex matmuls on the spectrum
    blockmm_k<0><<<dim3(NPOS / 16, 8), dim3(192), 0, stream>>>(Xr, Xi, w1, b1, SS, Pr, Pi);
    blockmm_k<1><<<dim3(NPOS / 16, 8), dim3(192), 0, stream>>>(Pr, Pi, w2, b2, nullptr, Qr, Qi);

    // inverse fft + bias + residual
    ifft_h<<<dim3(WF, EMBED / 32), dim3(256), 0, stream>>>(Qr, Qi, Sr, Si);
    irfft_w_add<<<dim3(HH, EMBED / 64), dim3(256), 0, stream>>>(Sr, Si, hln, x, Y);

    // ---- mlp branch ----
    layernorm_k<<<dim3(NPIX), dim3(256), 0, stream>>>(Y, n2w, n2b, nullptr, h2n);
    conv(mod, modb, (size_t)NPIX * EMBED);
    conv(mC1w, wMc1, (size_t)12288 * 768);
    conv(mC2w, wMc2, (size_t)6144 * 12288);
    conv(fc1w, wfc1, (size_t)3072 * 768);
    conv(fc2w, wfc2, (size_t)768 * 3072);

    // chunk the 16384 rows by 4096 so the 12288-wide hidden never fully materializes
    for (int m0 = 0; m0 < NPIX; m0 += 4096) {
        gemm_bt<0><<<dim3(12288 / BN, 4096 / BM), dim3(256), 0, stream>>>(
            modb + (size_t)m0 * EMBED, wMc1, mC1b, nullptr, Hm, 4096, 12288, 768);
        gemm_bt<0><<<dim3(6144 / BN, 4096 / BM), dim3(256), 0, stream>>>(
            Hm, wMc2, mC2b, nullptr, SS2c, 4096, 6144, 12288);
        gemm_bt<2><<<dim3(3072 / BN, 4096 / BM), dim3(256), 0, stream>>>(
            h2n + (size_t)m0 * EMBED, wfc1, fc1b, SS2c, Hf, 4096, 3072, 768);
        gemm_bt<3><<<dim3(768 / BN, 4096 / BM), dim3(256), 0, stream>>>(
            Hf, wfc2, fc2b, Y + (size_t)m0 * EMBED, (float*)d_out + (size_t)m0 * EMBED,
            4096, 768, 3072);
    }
}

// Round 2
// 4743.546 us; speedup vs baseline: 1.3677x; 1.3677x over previous
//
#include <hip/hip_runtime.h>
#include <hip/hip_fp16.h>

typedef unsigned short u16;
typedef unsigned int u32;
typedef unsigned char u8;
typedef __attribute__((ext_vector_type(8))) short short8;   // 8 x bf16 (4 VGPRs)
typedef __attribute__((ext_vector_type(4))) float f32x4;
typedef __attribute__((ext_vector_type(8))) int i32x8;

#define EMBED 768
#define HH 128
#define WW 128
#define WF 65            // 128/2 + 1
#define NPOS (HH*WF)     // 8320 spectral positions
#define NPIX (HH*WW)     // 16384 pixels
#define LATENT 3072
#define TWO_PI_OVER_128 0.049087385212340517f

__device__ __forceinline__ u16 f2b(float x) {
    u32 u = __float_as_uint(x);
    u32 r = u + 0x7FFFu + ((u >> 16) & 1u);   // RNE
    return (u16)(r >> 16);
}
__device__ __forceinline__ float b2f(u16 v) {
    return __uint_as_float(((u32)v) << 16);
}
__device__ __forceinline__ u8 f2fp8(float x) {
    // OCP e4m3fn via HW converter (saturating)
    return (u8)(__builtin_amdgcn_cvt_pk_fp8_f32(x, 0.f, 0, false) & 0xFF);
}

// ---------------------------------------------------------------------------
// LayerNorm over C=768. One 256-thread block per row; writes f32 and/or bf16.
// ---------------------------------------------------------------------------
__global__ __launch_bounds__(256)
void layernorm_k(const float* __restrict__ x, const float* __restrict__ w,
                 const float* __restrict__ bb, float* __restrict__ of,
                 u16* __restrict__ ob)
{
    int row = blockIdx.x;
    int t = threadIdx.x;
    const float* xr = x + (size_t)row * EMBED;
    float v0 = xr[t], v1 = xr[t + 256], v2 = xr[t + 512];
    float s = v0 + v1 + v2;
    float sq = v0 * v0 + v1 * v1 + v2 * v2;
    for (int off = 32; off > 0; off >>= 1) {
        s  += __shfl_xor(s, off, 64);
        sq += __shfl_xor(sq, off, 64);
    }
    __shared__ float rs[4], rq[4];
    int lane = t & 63, wv = t >> 6;
    if (lane == 0) { rs[wv] = s; rq[wv] = sq; }
    __syncthreads();
    s  = rs[0] + rs[1] + rs[2] + rs[3];
    sq = rq[0] + rq[1] + rq[2] + rq[3];
    float mean = s * (1.f / 768.f);
    float var  = sq * (1.f / 768.f) - mean * mean;
    float rstd = rsqrtf(var + 1e-5f);
    #pragma unroll
    for (int e = 0; e < 3; ++e) {
        int c = t + e * 256;
        float v = (e == 0 ? v0 : (e == 1 ? v1 : v2));
        float o = (v - mean) * rstd * w[c] + bb[c];
        size_t g = (size_t)row * EMBED + c;
        if (of) of[g] = o;
        if (ob) ob[g] = f2b(o);
    }
}

// ---------------------------------------------------------------------------
// Forward rfft along W
// ---------------------------------------------------------------------------
__global__ __launch_bounds__(256)
void rfft_w(const float* __restrict__ X, float* __restrict__ Tr, float* __restrict__ Ti)
{
    int h = blockIdx.x;
    int c0 = blockIdx.y << 6;
    __shared__ float xs[128 * 64];
    __shared__ float cs[128], sn[128];
    int t = threadIdx.x;
    for (int idx = t; idx < 8192; idx += 256)
        xs[idx] = X[((size_t)(h * WW + (idx >> 6))) * EMBED + c0 + (idx & 63)];
    if (t < 128) { float a = TWO_PI_OVER_128 * t; float ss, cc; sincosf(a, &ss, &cc); cs[t] = cc; sn[t] = ss; }
    __syncthreads();
    int c = t & 63, k0 = t >> 6;
    for (int k = k0; k < WF; k += 4) {
        float ar = 0.f, ai = 0.f;
        int j = 0;
        for (int w = 0; w < 128; ++w) {
            float v = xs[(w << 6) | c];
            ar += v * cs[j];
            ai -= v * sn[j];
            j = (j + k) & 127;
        }
        size_t g = ((size_t)(h * WF + k)) * EMBED + c0 + c;
        Tr[g] = ar; Ti[g] = ai;
    }
}

// ---------------------------------------------------------------------------
// Forward complex fft along H with 1/128 ortho scale.
// mode 0: f32 out. mode 1: bf16 packed [re rows | im rows].
// ---------------------------------------------------------------------------
__global__ __launch_bounds__(256)
void fft_h_fwd(const float* __restrict__ Tr, const float* __restrict__ Ti,
               float* __restrict__ Xr, float* __restrict__ Xi,
               u16* __restrict__ Mri, int mode)
{
    int k = blockIdx.x;
    int c0 = blockIdx.y << 5;
    __shared__ float sr[128 * 32], si[128 * 32];
    __shared__ float cs[128], sn[128];
    int t = threadIdx.x;
    for (int idx = t; idx < 4096; idx += 256) {
        int h = idx >> 5, c = idx & 31;
        size_t g = ((size_t)(h * WF + k)) * EMBED + c0 + c;
        sr[idx] = Tr[g]; si[idx] = Ti[g];
    }
    if (t < 128) { float a = TWO_PI_OVER_128 * t; float ss, cc; sincosf(a, &ss, &cc); cs[t] = cc; sn[t] = ss; }
    __syncthreads();
    int c = t & 31, u0 = t >> 5;
    for (int u = u0; u < 128; u += 8) {
        float ar = 0.f, ai = 0.f;
        int j = 0;
        for (int h = 0; h < 128; ++h) {
            float tr = sr[(h << 5) + c], ti = si[(h << 5) + c];
            float wc = cs[j], ws = sn[j];
            ar += tr * wc + ti * ws;
            ai += ti * wc - tr * ws;
            j = (j + u) & 127;
        }
        ar *= (1.f / 128.f); ai *= (1.f / 128.f);
        size_t p = (size_t)(u * WF + k);
        if (mode == 0) {
            Xr[p * EMBED + c0 + c] = ar;
            Xi[p * EMBED + c0 + c] = ai;
        } else {
            Mri[p * EMBED + c0 + c] = f2b(ar);
            Mri[(p + NPOS) * EMBED + c0 + c] = f2b(ai);
        }
    }
}

// ---------------------------------------------------------------------------
// Inverse complex fft along H (e^{+i}, no scale).
// ---------------------------------------------------------------------------
__global__ __launch_bounds__(256)
void ifft_h(const float* __restrict__ Qr, const float* __restrict__ Qi,
            float* __restrict__ Sr, float* __restrict__ Si)
{
    int k = blockIdx.x;
    int c0 = blockIdx.y << 5;
    __shared__ float sr[128 * 32], si[128 * 32];
    __shared__ float cs[128], sn[128];
    int t = threadIdx.x;
    for (int idx = t; idx < 4096; idx += 256) {
        int u = idx >> 5, c = idx & 31;
        size_t g = ((size_t)(u * WF + k)) * EMBED + c0 + c;
        sr[idx] = Qr[g]; si[idx] = Qi[g];
    }
    if (t < 128) { float a = TWO_PI_OVER_128 * t; float ss, cc; sincosf(a, &ss, &cc); cs[t] = cc; sn[t] = ss; }
    __syncthreads();
    int c = t & 31, h0 = t >> 5;
    for (int h = h0; h < 128; h += 8) {
        float ar = 0.f, ai = 0.f;
        int j = 0;
        for (int u = 0; u < 128; ++u) {
            float tr = sr[(u << 5) + c], ti = si[(u << 5) + c];
            float wc = cs[j], ws = sn[j];
            ar += tr * wc - ti * ws;
            ai += ti * wc + tr * ws;
            j = (j + h) & 127;
        }
        size_t g = ((size_t)(h * WF + k)) * EMBED + c0 + c;
        Sr[g] = ar; Si[g] = ai;
    }
}

// ---------------------------------------------------------------------------
// Inverse rfft along W (hermitian recombine, 1/128 scale) + bias + residual.
// ---------------------------------------------------------------------------
__global__ __launch_bounds__(256)
void irfft_w_add(const float* __restrict__ Sr, const float* __restrict__ Si,
                 const float* __restrict__ hln, const float* __restrict__ xin,
                 float* __restrict__ Y)
{
    int h = blockIdx.x;
    int c0 = blockIdx.y << 6;
    __shared__ float sr[WF * 64], si[WF * 64];
    __shared__ float cs[128], sn[128];
    int t = threadIdx.x;
    for (int idx = t; idx < WF * 64; idx += 256) {
        int k = idx >> 6, c = idx & 63;
        size_t g = ((size_t)(h * WF + k)) * EMBED + c0 + c;
        sr[idx] = Sr[g]; si[idx] = Si[g];
    }
    if (t < 128) { float a = TWO_PI_OVER_128 * t; float ss, cc; sincosf(a, &ss, &cc); cs[t] = cc; sn[t] = ss; }
    __syncthreads();
    int c = t & 63, w0 = t >> 6;
    for (int w = w0; w < 128; w += 4) {
        float acc = sr[c] + ((w & 1) ? -sr[(64 << 6) + c] : sr[(64 << 6) + c]);
        int j = 0;
        for (int k = 1; k < 64; ++k) {
            j = (j + w) & 127;
            acc += 2.f * (sr[(k << 6) + c] * cs[j] - si[(k << 6) + c] * sn[j]);
        }
        acc *= (1.f / 128.f);
        size_t g = ((size_t)(h * WW + w)) * EMBED + c0 + c;
        Y[g] = acc + hln[g] + xin[g];
    }
}

// ---------------------------------------------------------------------------
// Block-diagonal complex matmul (8 blocks of 96x96) with fused epilogue.
// ---------------------------------------------------------------------------
template<int SHRINK>
__global__ __launch_bounds__(192)
void blockmm_k(const float* __restrict__ Ir, const float* __restrict__ Ii,
               const float* __restrict__ wmat, const float* __restrict__ bvec,
               const float* __restrict__ SS, float* __restrict__ Or, float* __restrict__ Oi)
{
    int b = blockIdx.y;
    int p0 = blockIdx.x << 4;
    __shared__ __half2 wri[96 * 96];
    __shared__ float xr_s[16 * 96], xi_s[16 * 96];
    int t = threadIdx.x;
    for (int idx = t; idx < 96 * 96; idx += 192) {
        int i = idx / 96, o = idx - i * 96;
        float wr = wmat[((size_t)(b) * 96 + i) * 96 + o];
        float wi = wmat[((size_t)(8 + b) * 96 + i) * 96 + o];
        wri[idx] = __floats2half2_rn(wr, wi);
    }
    for (int idx = t; idx < 16 * 96; idx += 192) {
        int pp = idx / 96, cc = idx - pp * 96;
        size_t g = (size_t)(p0 + pp) * EMBED + b * 96 + cc;
        xr_s[idx] = Ir[g]; xi_s[idx] = Ii[g];
    }
    __syncthreads();
    int o = t % 96, pr = t / 96;
    float br = bvec[b * 96 + o], bi = bvec[(8 + b) * 96 + o];
    for (int pp = pr; pp < 16; pp += 2) {
        float ar = br, ai = bi;
        const float* xrp = &xr_s[pp * 96];
        const float* xip = &xi_s[pp * 96];
        for (int i = 0; i < 96; ++i) {
            float2 wv = __half22float2(wri[i * 96 + o]);
            float xr = xrp[i], xi = xip[i];
            ar += xr * wv.x - xi * wv.y;
            ai += xi * wv.x + xr * wv.y;
        }
        int p = p0 + pp;
        int cg = b * 96 + o;
        size_t og = (size_t)p * EMBED + cg;
        if (SHRINK == 0) {
            float scr = 1.f + SS[(size_t)p * 1536 + cg];
            float shr = SS[(size_t)p * 1536 + 768 + cg];
            float sci = 1.f + SS[((size_t)(NPOS + p)) * 1536 + cg];
            float shi = SS[((size_t)(NPOS + p)) * 1536 + 768 + cg];
            float nr = ar * scr - ai * sci + shr;
            float ni = ai * scr + ar * sci + shi;
            Or[og] = fmaxf(nr, 0.f);
            Oi[og] = fmaxf(ni, 0.f);
        } else {
            float r  = (ar > 0.01f) ? ar - 0.01f : ((ar < -0.01f) ? ar + 0.01f : 0.f);
            float im = (ai > 0.01f) ? ai - 0.01f : ((ai < -0.01f) ? ai + 0.01f : 0.f);
            Or[og] = r; Oi[og] = im;
        }
    }
}

// ---------------------------------------------------------------------------
// conversions
// ---------------------------------------------------------------------------
__global__ __launch_bounds__(256)
void f32_to_bf16_k(const float* __restrict__ in, u16* __restrict__ out, int n4)
{
    int i = blockIdx.x * 256 + threadIdx.x;
    if (i < n4) {
        float4 v = ((const float4*)in)[i];
        ushort4 o;
        o.x = f2b(v.x); o.y = f2b(v.y); o.z = f2b(v.z); o.w = f2b(v.w);
        ((ushort4*)out)[i] = o;
    }
}

__global__ __launch_bounds__(256)
void f32_to_fp8_k(const float* __restrict__ in, u8* __restrict__ out, float scale, int n4)
{
    int i = blockIdx.x * 256 + threadIdx.x;
    if (i < n4) {
        float4 v = ((const float4*)in)[i];
        u32 lo = __builtin_amdgcn_cvt_pk_fp8_f32(v.x * scale, v.y * scale, 0, false) & 0xFFFFu;
        u32 hi = __builtin_amdgcn_cvt_pk_fp8_f32(v.z * scale, v.w * scale, 0, false) & 0xFFFFu;
        ((u32*)out)[i] = lo | (hi << 16);
    }
}

// ---------------------------------------------------------------------------
// bf16 MFMA GEMM: C[M,N] = A[M,K] * B[N,K]^T, fp32 accumulate. 128x128 tile.
// EPI 0: bias+relu -> bf16.   EPI 1: bias+relu -> f32.
// EPI 2: bias, modulate with bf16 SS2 (ld 6144), exact gelu -> bf16.
// EPI 3: bias + aux_f32 -> f32.   EPI 4: bias+relu -> fp8 e4m3 (scale 1).
// ---------------------------------------------------------------------------
#define BM 128
#define BN 128
#define BK 64
#define LDK 72   // +8 elems pad: 8 distinct bank offsets = b128 bandwidth floor

template<int EPI>
__global__ __launch_bounds__(256, 2)
void gemm_bt(const u16* __restrict__ A, const u16* __restrict__ B,
             const float* __restrict__ bias, const void* __restrict__ aux,
             void* __restrict__ out, int M, int N, int K)
{
    __shared__ __align__(16) u16 As[BM * LDK];
    __shared__ __align__(16) u16 Bs[BN * LDK];
    int t = threadIdx.x;
    int bn0 = blockIdx.x * BN;
    int bm0 = blockIdx.y * BM;
    int lane = t & 63, wv = t >> 6;
    int wm = (wv & 1) << 6, wn = (wv >> 1) << 6;
    int lr = lane & 15, quad = lane >> 4;

    f32x4 acc[4][4];
    f32x4 zero = {0.f, 0.f, 0.f, 0.f};
    #pragma unroll
    for (int i = 0; i < 4; ++i)
        #pragma unroll
        for (int j = 0; j < 4; ++j) acc[i][j] = zero;

    for (int kt = 0; kt < K; kt += BK) {
        #pragma unroll
        for (int i = 0; i < 4; ++i) {
            int chunk = t + (i << 8);
            int row = chunk >> 3;
            int kc  = (chunk & 7) << 3;
            *(uint4*)&As[row * LDK + kc] = *(const uint4*)(A + (size_t)(bm0 + row) * K + kt + kc);
            *(uint4*)&Bs[row * LDK + kc] = *(const uint4*)(B + (size_t)(bn0 + row) * K + kt + kc);
        }
        __syncthreads();
        #pragma unroll
        for (int kk = 0; kk < BK; kk += 32) {
            short8 af[4], bf[4];
            #pragma unroll
            for (int i = 0; i < 4; ++i)
                af[i] = *(const short8*)&As[(wm + (i << 4) + lr) * LDK + kk + (quad << 3)];
            #pragma unroll
            for (int j = 0; j < 4; ++j)
                bf[j] = *(const short8*)&Bs[(wn + (j << 4) + lr) * LDK + kk + (quad << 3)];
            #pragma unroll
            for (int i = 0; i < 4; ++i)
                #pragma unroll
                for (int j = 0; j < 4; ++j)
                    acc[i][j] = __builtin_amdgcn_mfma_f32_16x16x32_bf16(af[i], bf[j], acc[i][j], 0, 0, 0);
        }
        __syncthreads();
    }

    #pragma unroll
    for (int j = 0; j < 4; ++j) {
        int gn = bn0 + wn + (j << 4) + lr;
        float bv = bias[gn];
        #pragma unroll
        for (int i = 0; i < 4; ++i) {
            int rm = bm0 + wm + (i << 4) + (quad << 2);
            #pragma unroll
            for (int r = 0; r < 4; ++r) {
                int gm = rm + r;
                float v = acc[i][j][r] + bv;
                size_t oidx = (size_t)gm * N + gn;
                if (EPI == 0) {
                    ((u16*)out)[oidx] = f2b(fmaxf(v, 0.f));
                } else if (EPI == 1) {
                    ((float*)out)[oidx] = fmaxf(v, 0.f);
                } else if (EPI == 2) {
                    const u16* ss = (const u16*)aux;
                    size_t si = (size_t)gm * (2 * LATENT) + gn;
                    float sc = 1.f + b2f(ss[si]);
                    float sh = b2f(ss[si + LATENT]);
                    v = v * sc + sh;
                    v = 0.5f * v * (1.f + erff(v * 0.70710678118f));
                    ((u16*)out)[oidx] = f2b(v);
                } else if (EPI == 3) {
                    const float* y = (const float*)aux;
                    ((float*)out)[oidx] = v + y[oidx];
                } else {
                    ((u8*)out)[oidx] = f2fp8(fmaxf(v, 0.f));
                }
            }
        }
    }
}

// ---------------------------------------------------------------------------
// MX-fp8 MFMA GEMM: C[M,N] = A[M,K] * B[N,K]^T.  A in e4m3 (scale 2^0),
// B in e4m3 pre-scaled by 2^7 (HW scale byte 120 = 2^-7).  BK=128.
// Uniform scale bytes replicated -> immune to scale-block mapping details.
// Epilogue: bias + relu -> bf16.
// ---------------------------------------------------------------------------
#define LDK8 144   // 128 + 16B pad

__global__ __launch_bounds__(256, 2)
void gemm_f8(const u8* __restrict__ A, const u8* __restrict__ B,
             const float* __restrict__ bias, u16* __restrict__ out,
             int M, int N, int K)
{
    __shared__ __align__(16) u8 As[128 * LDK8];
    __shared__ __align__(16) u8 Bs[128 * LDK8];
    int t = threadIdx.x;
    int bn0 = blockIdx.x * 128;
    int bm0 = blockIdx.y * 128;
    int lane = t & 63, wv = t >> 6;
    int wm = (wv & 1) << 6, wn = (wv >> 1) << 6;
    int lr = lane & 15, quad = lane >> 4;

    f32x4 acc[4][4];
    f32x4 zero = {0.f, 0.f, 0.f, 0.f};
    #pragma unroll
    for (int i = 0; i < 4; ++i)
        #pragma unroll
        for (int j = 0; j < 4; ++j) acc[i][j] = zero;

    for (int kt = 0; kt < K; kt += 128) {
        #pragma unroll
        for (int i = 0; i < 4; ++i) {
            int chunk = t + (i << 8);            // 0..1023 of 16B units
            int row = chunk >> 3;
            int c16 = (chunk & 7) << 4;
            *(uint4*)&As[row * LDK8 + c16] = *(const uint4*)(A + (size_t)(bm0 + row) * K + kt + c16);
            *(uint4*)&Bs[row * LDK8 + c16] = *(const uint4*)(B + (size_t)(bn0 + row) * K + kt + c16);
        }
        __syncthreads();
        union { i32x8 v; uint4 q[2]; } af[4], bg[4];
        #pragma unroll
        for (int i = 0; i < 4; ++i) {
            const u8* p = &As[(wm + (i << 4) + lr) * LDK8 + (quad << 5)];
            af[i].q[0] = *(const uint4*)p;
            af[i].q[1] = *(const uint4*)(p + 16);
        }
        #pragma unroll
        for (int j = 0; j < 4; ++j) {
            const u8* p = &Bs[(wn + (j << 4) + lr) * LDK8 + (quad << 5)];
            bg[j].q[0] = *(const uint4*)p;
            bg[j].q[1] = *(const uint4*)(p + 16);
        }
        #pragma unroll
        for (int i = 0; i < 4; ++i)
            #pragma unroll
            for (int j = 0; j < 4; ++j)
                acc[i][j] = __builtin_amdgcn_mfma_scale_f32_16x16x128_f8f6f4(
                    af[i].v, bg[j].v, acc[i][j],
                    0, 0,                       // A fmt fp8, B fmt fp8
                    0, 0x7F7F7F7F,              // scale A = 2^0 (replicated)
                    0, 0x78787878);             // scale B = 2^-7 (replicated)
        __syncthreads();
    }

    #pragma unroll
    for (int j = 0; j < 4; ++j) {
        int gn = bn0 + wn + (j << 4) + lr;
        float bv = bias[gn];
        #pragma unroll
        for (int i = 0; i < 4; ++i) {
            int rm = bm0 + wm + (i << 4) + (quad << 2);
            #pragma unroll
            for (int r = 0; r < 4; ++r) {
                int gm = rm + r;
                float v = acc[i][j][r] + bv;
                out[(size_t)gm * N + gn] = f2b(fmaxf(v, 0.f));
            }
        }
    }
}

// ---------------------------------------------------------------------------
extern "C" void kernel_launch(void* const* d_in, const int* in_sizes, int n_in,
                              void* d_out, int out_size, void* d_ws, size_t ws_size,
                              hipStream_t stream)
{
    if (n_in < 22 || out_size != NPIX * EMBED) return;

    const float* x    = (const float*)d_in[0];
    const float* mod  = (const float*)d_in[1];
    const float* n1w  = (const float*)d_in[2];
    const float* n1b  = (const float*)d_in[3];
    const float* n2w  = (const float*)d_in[4];
    const float* n2b  = (const float*)d_in[5];
    const float* w1   = (const float*)d_in[6];
    const float* b1   = (const float*)d_in[7];
    const float* w2   = (const float*)d_in[8];
    const float* b2   = (const float*)d_in[9];
    const float* fC1w = (const float*)d_in[10];
    const float* fC1b = (const float*)d_in[11];
    const float* fC2w = (const float*)d_in[12];
    const float* fC2b = (const float*)d_in[13];
    const float* fc1w = (const float*)d_in[14];
    const float* fc1b = (const float*)d_in[15];
    const float* fc2w = (const float*)d_in[16];
    const float* fc2b = (const float*)d_in[17];
    const float* mC1w = (const float*)d_in[18];
    const float* mC1b = (const float*)d_in[19];
    const float* mC2w = (const float*)d_in[20];
    const float* mC2b = (const float*)d_in[21];

    char* ws = (char*)d_ws;
    size_t off = 0;
    auto alloc = [&](size_t bytes) { size_t o = off; off += (bytes + 255) & ~(size_t)255; return o; };

    const size_t F32_PIX = (size_t)NPIX * EMBED * 4;
    const size_t F32_POS = (size_t)NPOS * EMBED * 4;

    float* hln = (float*)(ws + alloc(F32_PIX));
    float* Y   = (float*)(ws + alloc(F32_PIX));
    float* Tr  = (float*)(ws + alloc(F32_POS));        // later: Hf (full-M, bf16)
    float* Ti  = (float*)(ws + alloc(F32_POS));
    float* Xr  = (float*)(ws + alloc(F32_POS));
    float* Xi  = (float*)(ws + alloc(F32_POS));
    u16*   Mri = (u16*)(ws + alloc((size_t)2 * NPOS * EMBED * 2));   // later: h2n
    u16*   modb = (u16*)(ws + alloc((size_t)NPIX * EMBED * 2));
    char*  R1  = ws + alloc((size_t)16640 * 3072 * 2); // H1 / Hm8 chunk
    char*  R2  = ws + alloc((size_t)16640 * 1536 * 4); // SS / Qr,Qi / SS2 chunk

    u16* wFc1 = (u16*)(ws + alloc((size_t)3072 * 768 * 2));
    u16* wFc2 = (u16*)(ws + alloc((size_t)1536 * 3072 * 2));
    u16* wfc1 = (u16*)(ws + alloc((size_t)3072 * 768 * 2));
    u16* wfc2 = (u16*)(ws + alloc((size_t)768 * 3072 * 2));
    u16* wMc1 = (u16*)(ws + alloc((size_t)12288 * 768 * 2));
    u8*  wMc2f8 = (u8*)(ws + alloc((size_t)6144 * 12288));

    if (off > ws_size) return;

    u16*   H1   = (u16*)R1;
    u8*    Hm8  = (u8*)R1;
    float* SS   = (float*)R2;
    float* Qr   = (float*)R2;
    float* Qi   = (float*)(R2 + F32_POS);
    u16*   SS2c = (u16*)R2;
    float* Sr   = Xr;
    float* Si   = Xi;
    float* Pr   = Tr;
    float* Pi   = Ti;
    u16*   h2n  = Mri;
    u16*   Hf   = (u16*)Tr;     // 16384x3072 bf16 = 100.7 MB over Tr..Xi (102.2 MB)

    auto conv = [&](const float* src, u16* dst, size_t n) {
        int n4 = (int)(n >> 2);
        f32_to_bf16_k<<<dim3((n4 + 255) / 256), dim3(256), 0, stream>>>(src, dst, n4);
    };

    // ---- filter branch ----
    layernorm_k<<<dim3(NPIX), dim3(256), 0, stream>>>(x, n1w, n1b, hln, nullptr);
    rfft_w<<<dim3(HH, EMBED / 64), dim3(256), 0, stream>>>(hln, Tr, Ti);
    fft_h_fwd<<<dim3(WF, EMBED / 32), dim3(256), 0, stream>>>(Tr, Ti, Xr, Xi, nullptr, 0);
    rfft_w<<<dim3(HH, EMBED / 64), dim3(256), 0, stream>>>(mod, Tr, Ti);
    fft_h_fwd<<<dim3(WF, EMBED / 32), dim3(256), 0, stream>>>(Tr, Ti, nullptr, nullptr, Mri, 1);

    conv(fC1w, wFc1, (size_t)3072 * 768);
    conv(fC2w, wFc2, (size_t)1536 * 3072);

    gemm_bt<0><<<dim3(3072 / BN, 16640 / BM), dim3(256), 0, stream>>>(
        Mri, wFc1, fC1b, nullptr, H1, 16640, 3072, 768);
    gemm_bt<1><<<dim3(1536 / BN, 16640 / BM), dim3(256), 0, stream>>>(
        H1, wFc2, fC2b, nullptr, SS, 16640, 1536, 3072);

    blockmm_k<0><<<dim3(NPOS / 16, 8), dim3(192), 0, stream>>>(Xr, Xi, w1, b1, SS, Pr, Pi);
    blockmm_k<1><<<dim3(NPOS / 16, 8), dim3(192), 0, stream>>>(Pr, Pi, w2, b2, nullptr, Qr, Qi);

    ifft_h<<<dim3(WF, EMBED / 32), dim3(256), 0, stream>>>(Qr, Qi, Sr, Si);
    irfft_w_add<<<dim3(HH, EMBED / 64), dim3(256), 0, stream>>>(Sr, Si, hln, x, Y);

    // ---- mlp branch ----
    layernorm_k<<<dim3(NPIX), dim3(256), 0, stream>>>(Y, n2w, n2b, nullptr, h2n);
    conv(mod, modb, (size_t)NPIX * EMBED);
    conv(mC1w, wMc1, (size_t)12288 * 768);
    conv(fc1w, wfc1, (size_t)3072 * 768);
    conv(fc2w, wfc2, (size_t)768 * 3072);
    {   // mC2 weights -> fp8, pre-scaled by 2^7 (HW applies 2^-7)
        int n4 = (int)(((size_t)6144 * 12288) >> 2);
        f32_to_fp8_k<<<dim3((n4 + 255) / 256), dim3(256), 0, stream>>>(mC2w, wMc2f8, 128.f, n4);
    }

    for (int m0 = 0; m0 < NPIX; m0 += 4096) {
        gemm_bt<4><<<dim3(12288 / BN, 4096 / BM), dim3(256), 0, stream>>>(
            modb + (size_t)m0 * EMBED, wMc1, mC1b, nullptr, Hm8, 4096, 12288, 768);
        gemm_f8<<<dim3(6144 / 128, 4096 / 128), dim3(256), 0, stream>>>(
            Hm8, wMc2f8, mC2b, SS2c, 4096, 6144, 12288);
        gemm_bt<2><<<dim3(3072 / BN, 4096 / BM), dim3(256), 0, stream>>>(
            h2n + (size_t)m0 * EMBED, wfc1, fc1b, SS2c, Hf + (size_t)m0 * LATENT,
            4096, 3072, 768);
    }
    gemm_bt<3><<<dim3(768 / BN, NPIX / BM), dim3(256), 0, stream>>>(
        Hf, wfc2, fc2b, Y, (float*)d_out, NPIX, 768, 3072);
}